// Round 6
// baseline (202.010 us; speedup 1.0000x reference)
//
#include <hip/hip_runtime.h>

// CBC (classification-by-components) fused kernel, v5.
// x:[B,1024] f32, components:[5,1024] f32, reasonings:[5,3,2] f32 -> probs:[B,3] f32.
//
// Evidence so far: v1 (regs) 35us, v2 (deep-ILP mess) 45us, v3 (spill) 140us,
// v4 (LDS comps) 39us. Occupancy was NOT the limiter (v4 >= v1 occupancy, no
// gain). Little's-law analysis: delivery 6.2 B/cyc/CU vs 10.25 achievable ->
// per-wave load duty-cycle ~10-20%, because each row is a strictly serial
// {load -> drain -> ~1500cyc compute+butterfly+store} chain with no loads in
// flight during the tail.
//
// v5 = v4 + DEPTH-1 CROSS-ROW PREFETCH: issue next row's 4 dwordx4 at the top
// of the body, before current row's compute/reduction. The tail now covers the
// ~900cyc HBM latency. +16 VGPR (est ~65 total) -- affordable only with
// components in LDS (v4's layout is the enabler; in-reg comps would hit the
// 128-VGPR/3-wave cliff). __launch_bounds__(256,4): spill-safe budget.
// 1024 blocks x 256 thr = 4096 waves, 8 rows/wave -> 7/8 iterations overlapped.

#define DD 1024
#define KK 5
#define CC 3
#define F4R (DD / 4)          // 256 float4 per row
#define JN (F4R / 64)         // 4 j-steps per lane

__global__ __launch_bounds__(256, 4) void cbc_kernel(
    const float* __restrict__ x,
    const float* __restrict__ comps,
    const float* __restrict__ reas,
    float* __restrict__ out,
    int B)
{
    __shared__ float4 cl[KK * F4R];   // 20480 B

    const int tid  = threadIdx.x;
    const int lane = tid & 63;
    const int waves_per_block = blockDim.x >> 6;
    const int wave    = blockIdx.x * waves_per_block + (tid >> 6);
    const int n_waves = gridDim.x * waves_per_block;

    const float4* x4 = (const float4*)x;

    // ---- issue first row's loads immediately (overlaps LDS staging) ----
    int row = wave;
    float4 xv[JN];
    if (row < B) {
        const float4* p = x4 + (size_t)row * F4R + lane;
#pragma unroll
        for (int j = 0; j < JN; ++j) xv[j] = p[j * 64];
    }

    // ---- stage components into LDS (coalesced float4; 5 iters/thread) ----
    const float4* c4 = (const float4*)comps;
    for (int i = tid; i < KK * F4R; i += blockDim.x) cl[i] = c4[i];

    // ---- per-lane reasoning params for class c = lane (lanes >= 3 dummy) ----
    // pk = A; nk = (1-A)*B; w = pk-nk; bias = sum nk; invden = 1/sum(pk+nk)
    const int c = (lane < CC) ? lane : 0;
    float wv[KK], bias = 0.f, den = 0.f;
#pragma unroll
    for (int k = 0; k < KK; ++k) {
        float a = reas[k * (CC * 2) + c * 2 + 0];
        float b = reas[k * (CC * 2) + c * 2 + 1];
        a = fminf(fmaxf(a, 0.f), 1.f);
        b = fminf(fmaxf(b, 0.f), 1.f);
        float nk = (1.f - a) * b;
        wv[k] = a - nk;
        bias += nk;
        den  += a + nk;
    }
    const float invden = 1.f / den;

    __syncthreads();

    if (row < B) {
        while (true) {
            const int  next = row + n_waves;
            const bool hn   = next < B;

            // ---- PREFETCH next row before any compute: stays in flight
            //      across the ~1500cyc compute+butterfly+store tail ----
            float4 xn[JN];
            if (hn) {
                const float4* pn = x4 + (size_t)next * F4R + lane;
#pragma unroll
                for (int j = 0; j < JN; ++j) xn[j] = pn[j * 64];
            }

            // ---- d^2 partials (diff form, exact vs reference) ----
            float acc[KK];
#pragma unroll
            for (int k = 0; k < KK; ++k) acc[k] = 0.f;

#pragma unroll
            for (int j = 0; j < JN; ++j) {
#pragma unroll
                for (int k = 0; k < KK; ++k) {
                    float4 cv = cl[k * F4R + j * 64 + lane];
                    float dx = xv[j].x - cv.x;
                    float dy = xv[j].y - cv.y;
                    float dz = xv[j].z - cv.z;
                    float dw = xv[j].w - cv.w;
                    acc[k] += dx * dx;
                    acc[k] += dy * dy;
                    acc[k] += dz * dz;
                    acc[k] += dw * dw;
                }
            }

            // ---- 64-lane butterfly: all lanes end with full d2[k] ----
#pragma unroll
            for (int k = 0; k < KK; ++k) {
#pragma unroll
                for (int off = 32; off > 0; off >>= 1)
                    acc[k] += __shfl_xor(acc[k], off, 64);
            }

            // ---- epilogue: lanes 0..2 write this row's 3 class probs ----
            if (lane < CC) {
                float num = bias;
#pragma unroll
                for (int k = 0; k < KK; ++k)
                    num += __expf(-0.5f * acc[k]) * wv[k];   // variance = 1
                out[(size_t)row * CC + lane] = num * invden;
            }

            if (!hn) break;
#pragma unroll
            for (int j = 0; j < JN; ++j) xv[j] = xn[j];
            row = next;
        }
    }
}

extern "C" void kernel_launch(void* const* d_in, const int* in_sizes, int n_in,
                              void* d_out, int out_size, void* d_ws, size_t ws_size,
                              hipStream_t stream) {
    const float* x = (const float*)d_in[0];
    const float* comps = (const float*)d_in[1];
    const float* reas = (const float*)d_in[2];
    float* out = (float*)d_out;
    const int B = in_sizes[0] / DD;   // 32768 rows

    // 1024 blocks x 256 threads = 4096 waves, 8 rows/wave grid-stride:
    // 7 of 8 iterations have the next row's loads in flight during compute.
    const int blocks = 1024;
    cbc_kernel<<<blocks, 256, 0, stream>>>(x, comps, reas, out, B);
}

// Round 7
// 199.271 us; speedup vs baseline: 1.0137x; 1.0137x over previous
//
#include <hip/hip_runtime.h>

// CBC (classification-by-components) fused kernel, v6.
// x:[B,1024] f32, components:[5,1024] f32, reasonings:[5,3,2] f32 -> probs:[B,3] f32.
//
// History: v1 regs 35us / v4 LDS-comps 39us / v5 prefetch+copy 47us.
// v5 failed because the xv=xn copy loop forced a vmcnt(0) drain (copy source =
// newest loads) right after the store, lengthening the serial chain.
// v6: ping-pong double buffer with NAMED buffers (no copies, all static
// indices), unconditional prefetch with tail address clamped to the current
// row (L2-hot re-read instead of a branch). The compiler can then emit counted
// vmcnt(N) waits: consumed buffer's loads are 5 vmem ops old at use. Each
// wave keeps 4KB in flight ~100% of its row period -> outstanding bytes/CU
// rise ~2x over v1 -> delivery should approach the BW roofline.
// Components in LDS (20KB/block): keeps VGPR ~70 (< 128 cap, 4 waves/SIMD).

#define DD 1024
#define KK 5
#define CC 3
#define F4R (DD / 4)          // 256 float4 per row
#define JN (F4R / 64)         // 4 j-steps per lane

__global__ __launch_bounds__(256, 4) void cbc_kernel(
    const float* __restrict__ x,
    const float* __restrict__ comps,
    const float* __restrict__ reas,
    float* __restrict__ out,
    int B)
{
    __shared__ float4 cl[KK * F4R];   // 20480 B

    const int tid  = threadIdx.x;
    const int lane = tid & 63;
    const int waves_per_block = blockDim.x >> 6;
    const int wave    = blockIdx.x * waves_per_block + (tid >> 6);
    const int n_waves = gridDim.x * waves_per_block;

    const float4* x4 = (const float4*)x;

    // ---- issue first row's loads immediately (overlaps LDS staging) ----
    const int row0 = (wave < B) ? wave : 0;
    float4 xA[JN], xB[JN];
    {
        const float4* p = x4 + (size_t)row0 * F4R + lane;
#pragma unroll
        for (int j = 0; j < JN; ++j) xA[j] = p[j * 64];
    }

    // ---- stage components into LDS (coalesced float4; 5 iters/thread) ----
    const float4* c4 = (const float4*)comps;
    for (int i = tid; i < KK * F4R; i += blockDim.x) cl[i] = c4[i];

    // ---- per-lane reasoning params for class c = lane (lanes >= 3 dummy) ----
    const int c = (lane < CC) ? lane : 0;
    float wv[KK], bias = 0.f, den = 0.f;
#pragma unroll
    for (int k = 0; k < KK; ++k) {
        float a = reas[k * (CC * 2) + c * 2 + 0];
        float b = reas[k * (CC * 2) + c * 2 + 1];
        a = fminf(fmaxf(a, 0.f), 1.f);
        b = fminf(fmaxf(b, 0.f), 1.f);
        float nk = (1.f - a) * b;
        wv[k] = a - nk;
        bias += nk;
        den  += a + nk;
    }
    const float invden = 1.f / den;

    __syncthreads();

    // compute + reduce + store one row from buffer BUF
#define COMPUTE_ROW(BUF, ROW)                                              \
    {                                                                      \
        float acc[KK];                                                     \
        _Pragma("unroll")                                                  \
        for (int k = 0; k < KK; ++k) acc[k] = 0.f;                         \
        _Pragma("unroll")                                                  \
        for (int j = 0; j < JN; ++j) {                                     \
            _Pragma("unroll")                                              \
            for (int k = 0; k < KK; ++k) {                                 \
                float4 cv = cl[k * F4R + j * 64 + lane];                   \
                float dx = BUF[j].x - cv.x;                                \
                float dy = BUF[j].y - cv.y;                                \
                float dz = BUF[j].z - cv.z;                                \
                float dw = BUF[j].w - cv.w;                                \
                acc[k] += dx * dx;                                         \
                acc[k] += dy * dy;                                         \
                acc[k] += dz * dz;                                         \
                acc[k] += dw * dw;                                         \
            }                                                              \
        }                                                                  \
        _Pragma("unroll")                                                  \
        for (int k = 0; k < KK; ++k) {                                     \
            _Pragma("unroll")                                              \
            for (int off = 32; off > 0; off >>= 1)                         \
                acc[k] += __shfl_xor(acc[k], off, 64);                     \
        }                                                                  \
        if (lane < CC) {                                                   \
            float num = bias;                                              \
            _Pragma("unroll")                                              \
            for (int k = 0; k < KK; ++k)                                   \
                num += __expf(-0.5f * acc[k]) * wv[k];                     \
            out[(size_t)(ROW) * CC + lane] = num * invden;                 \
        }                                                                  \
    }

    if (wave < B) {
        int row = wave;
        while (true) {
            // -- half 1: prefetch into xB (clamped: tail re-reads L2-hot row),
            //            compute xA --
            const int  n1 = row + n_waves;
            const bool h1 = n1 < B;
            {
                const int pf = h1 ? n1 : row;
                const float4* p = x4 + (size_t)pf * F4R + lane;
#pragma unroll
                for (int j = 0; j < JN; ++j) xB[j] = p[j * 64];
            }
            COMPUTE_ROW(xA, row)
            if (!h1) break;

            // -- half 2: prefetch into xA, compute xB --
            const int  n2 = n1 + n_waves;
            const bool h2 = n2 < B;
            {
                const int pf = h2 ? n2 : n1;
                const float4* p = x4 + (size_t)pf * F4R + lane;
#pragma unroll
                for (int j = 0; j < JN; ++j) xA[j] = p[j * 64];
            }
            COMPUTE_ROW(xB, n1)
            if (!h2) break;

            row = n2;
        }
    }
#undef COMPUTE_ROW
}

extern "C" void kernel_launch(void* const* d_in, const int* in_sizes, int n_in,
                              void* d_out, int out_size, void* d_ws, size_t ws_size,
                              hipStream_t stream) {
    const float* x = (const float*)d_in[0];
    const float* comps = (const float*)d_in[1];
    const float* reas = (const float*)d_in[2];
    float* out = (float*)d_out;
    const int B = in_sizes[0] / DD;   // 32768 rows

    // 1024 blocks x 256 threads = 4096 waves, 8 rows/wave grid-stride:
    // even count -> the ping-pong loop runs 4 full iterations, no odd tail.
    const int blocks = 1024;
    cbc_kernel<<<blocks, 256, 0, stream>>>(x, comps, reas, out, B);
}